// Round 1
// baseline (425.315 us; speedup 1.0000x reference)
//
#include <hip/hip_runtime.h>
#include <hip/hip_bf16.h>
#include <cstdint>
#include <cstddef>

// Problem constants
#define Bsz 4
#define Tsz 8192
#define Dsz 512
#define Hn 8
#define BSn 16
#define NBn 512     // T/BS blocks (attention sequence length)
#define DHn 64      // head dim
#define NQKV 1536   // 3*D
#define MROWS 32768 // B*T

typedef __attribute__((ext_vector_type(8))) short short8;
typedef __attribute__((ext_vector_type(4))) float float4f;

__device__ __forceinline__ uint16_t f2b(float f) {
  union { float f; uint32_t u; } v; v.f = f;
  uint32_t u = v.u;
  return (uint16_t)((u + 0x7fffu + ((u >> 16) & 1u)) >> 16);  // RNE
}
__device__ __forceinline__ float b2f(uint16_t h) {
  union { uint32_t u; float f; } v; v.u = ((uint32_t)h) << 16;
  return v.f;
}

// async 16B global -> LDS (wave-uniform LDS base + lane*16)
__device__ __forceinline__ void gl_lds16(const void* g, void* l) {
  __builtin_amdgcn_global_load_lds(
      (const __attribute__((address_space(1))) unsigned int*)g,
      (__attribute__((address_space(3))) unsigned int*)l, 16, 0, 0);
}

// ---------------- convert kernels ----------------
__global__ void cvt_x_kernel(const float* __restrict__ x, uint16_t* __restrict__ xb) {
  int i = (blockIdx.x * 256 + threadIdx.x) * 4;
  float4 v = *(const float4*)(x + i);
  union { uint16_t u16[4]; uint64_t u64; } o;
  o.u16[0] = f2b(v.x); o.u16[1] = f2b(v.y); o.u16[2] = f2b(v.z); o.u16[3] = f2b(v.w);
  *(uint64_t*)(xb + i) = o.u64;
}

__global__ void cvt_w_kernel(const float* __restrict__ Wq, const float* __restrict__ Wk,
                             const float* __restrict__ Wv, uint16_t* __restrict__ wc) {
  int i = (blockIdx.x * 256 + threadIdx.x) * 4;  // i < 1536*512
  int row = i >> 9;
  int col = i & 511;
  const float* src = (row < 512) ? Wq : ((row < 1024) ? Wk : Wv);
  float4 v = *(const float4*)(src + (size_t)(row & 511) * 512 + col);
  union { uint16_t u16[4]; uint64_t u64; } o;
  o.u16[0] = f2b(v.x); o.u16[1] = f2b(v.y); o.u16[2] = f2b(v.z); o.u16[3] = f2b(v.w);
  *(uint64_t*)(wc + i) = o.u64;
}

// ---------------- QKV projection GEMM ----------------
// C[M=32768, N=1536] = Xb[M,512] * Wc[N,512]^T + bias, bf16 out.
#define BM 128
#define BN 128
#define BK 32

__global__ __launch_bounds__(256) void gemm_qkv(
    const uint16_t* __restrict__ Xb, const uint16_t* __restrict__ Wc,
    const float* __restrict__ bq, const float* __restrict__ bkp,
    const float* __restrict__ bv, uint16_t* __restrict__ Yb) {
  __shared__ uint16_t As[BM * BK];
  __shared__ uint16_t Bs[BN * BK];
  const int tid = threadIdx.x;
  const int wave = tid >> 6, lane = tid & 63;
  const int lrow = lane & 15, quad = lane >> 4;
  const int m0 = blockIdx.x * BM;
  const int n0 = blockIdx.y * BN;
  const int wm = (wave >> 1) * 64, wn = (wave & 1) * 64;

  float4f acc[4][4] = {};

  for (int k0 = 0; k0 < Dsz; k0 += BK) {
    __syncthreads();  // LDS safe to overwrite
#pragma unroll
    for (int p = 0; p < 2; ++p) {
      int cbase = p * 256 + wave * 64;   // wave-uniform chunk base
      int c = cbase + lane;
      int row = c >> 2, kc = (c & 3) * 8;
      gl_lds16(Xb + (size_t)(m0 + row) * Dsz + k0 + kc, As + cbase * 8);
      gl_lds16(Wc + (size_t)(n0 + row) * Dsz + k0 + kc, Bs + cbase * 8);
    }
    __syncthreads();  // barrier drains vmcnt

    short8 af[4], bf[4];
#pragma unroll
    for (int i = 0; i < 4; ++i) {
      af[i] = *(const short8*)(As + (wm + i * 16 + lrow) * BK + quad * 8);
      bf[i] = *(const short8*)(Bs + (wn + i * 16 + lrow) * BK + quad * 8);
    }
#pragma unroll
    for (int i = 0; i < 4; ++i)
#pragma unroll
      for (int j = 0; j < 4; ++j)
        acc[i][j] = __builtin_amdgcn_mfma_f32_16x16x32_bf16(af[i], bf[j], acc[i][j], 0, 0, 0);
  }

  // epilogue: + bias, write bf16.  n0 tiles (128) never cross the 512 boundaries.
  const float* bias = (n0 < 512) ? bq : ((n0 < 1024) ? bkp : bv);
#pragma unroll
  for (int j = 0; j < 4; ++j) {
    int n = n0 + wn + j * 16 + lrow;
    float bval = bias[n & 511];
#pragma unroll
    for (int i = 0; i < 4; ++i) {
      int mr = m0 + wm + i * 16 + quad * 4;
#pragma unroll
      for (int r = 0; r < 4; ++r)
        Yb[(size_t)(mr + r) * NQKV + n] = f2b(acc[i][j][r] + bval);
    }
  }
}

// ---------------- fused block attention (flash-style) ----------------
#define QT 64   // q rows per block (16 per wave)
#define KT 32   // kv rows per iteration
#define VTS 40  // Vt LDS row stride (elems), 80B: 16B-aligned + bank-spread
#define PSS 40

__global__ __launch_bounds__(256) void attn_kernel(
    const uint16_t* __restrict__ Yb, float* __restrict__ out) {
  __shared__ uint16_t Ks[KT * DHn];     // [32][64] K rows
  __shared__ uint16_t Vt[DHn * VTS];    // [64][40] V transposed
  __shared__ uint16_t Ps[4][16 * PSS];  // per-wave P round-trip

  int bx = blockIdx.x;
  const int qt = bx & 7; bx >>= 3;
  const int h = bx & 7;  bx >>= 3;
  const int s = bx & 15;
  const int b = bx >> 4;

  const int tid = threadIdx.x;
  const int wave = tid >> 6, lane = tid & 63;
  const int lrow = lane & 15, quad = lane >> 4;

  const size_t seqbase = (size_t)b * Tsz + s;  // token row = seqbase + n*16

  // Q fragments for this wave's 16 rows (held in registers for whole kernel)
  const int nq = qt * QT + wave * 16 + lrow;
  const uint16_t* qp = Yb + (seqbase + (size_t)nq * BSn) * NQKV + h * DHn;
  short8 qf0 = *(const short8*)(qp + quad * 8);        // dh 0..31
  short8 qf1 = *(const short8*)(qp + 32 + quad * 8);   // dh 32..63

  float m_r[4], l_r[4];
  float4f o[4] = {};
#pragma unroll
  for (int r = 0; r < 4; ++r) { m_r[r] = -1e30f; l_r[r] = 0.f; }

  // scale folded with log2(e): softmax in exp2 domain (identical weights)
  const float scl = 0.04419417382415922f * 1.4426950408889634f;

  uint16_t* Psw = Ps[wave];

  for (int kv0 = 0; kv0 < NBn; kv0 += KT) {
    __syncthreads();
    {  // stage K tile [32][64] via async 16B loads: 256 chunks exactly
      int cbase = wave * 64;
      int c = cbase + lane;
      int krow = c >> 3, kc = (c & 7) * 8;
      gl_lds16(Yb + (seqbase + (size_t)(kv0 + krow) * BSn) * NQKV + Dsz + h * DHn + kc,
               Ks + cbase * 8);
    }
    {  // stage V tile transposed: each thread 8 elems of one row -> column writes
      int vrow = tid >> 3, d0 = (tid & 7) * 8;
      short8 vv = *(const short8*)(Yb + (seqbase + (size_t)(kv0 + vrow) * BSn) * NQKV +
                                   2 * Dsz + h * DHn + d0);
#pragma unroll
      for (int e = 0; e < 8; ++e) Vt[(d0 + e) * VTS + vrow] = (uint16_t)vv[e];
    }
    __syncthreads();

    // S[16 x 32] = Q * K^T (two 16-col halves, each K=64 over dh)
    float4f s0 = {}, s1 = {};
    {
      short8 kfa = *(const short8*)(Ks + lrow * DHn + quad * 8);
      short8 kfb = *(const short8*)(Ks + lrow * DHn + 32 + quad * 8);
      s0 = __builtin_amdgcn_mfma_f32_16x16x32_bf16(qf0, kfa, s0, 0, 0, 0);
      s0 = __builtin_amdgcn_mfma_f32_16x16x32_bf16(qf1, kfb, s0, 0, 0, 0);
      short8 kfc = *(const short8*)(Ks + (16 + lrow) * DHn + quad * 8);
      short8 kfd = *(const short8*)(Ks + (16 + lrow) * DHn + 32 + quad * 8);
      s1 = __builtin_amdgcn_mfma_f32_16x16x32_bf16(qf0, kfc, s1, 0, 0, 0);
      s1 = __builtin_amdgcn_mfma_f32_16x16x32_bf16(qf1, kfd, s1, 0, 0, 0);
    }

    // ---- online softmax (rows = quad*4+r, spread over 16 lanes) ----
    float a0[4], a1[4], rmax[4];
#pragma unroll
    for (int r = 0; r < 4; ++r) {
      a0[r] = s0[r] * scl; a1[r] = s1[r] * scl;
      rmax[r] = fmaxf(a0[r], a1[r]);
    }
#pragma unroll
    for (int off = 1; off < 16; off <<= 1)
#pragma unroll
      for (int r = 0; r < 4; ++r) rmax[r] = fmaxf(rmax[r], __shfl_xor(rmax[r], off));

    float alpha[4], psum[4];
    uint16_t pb0[4], pb1[4];
#pragma unroll
    for (int r = 0; r < 4; ++r) {
      float mnew = fmaxf(m_r[r], rmax[r]);
      alpha[r] = exp2f(m_r[r] - mnew);
      m_r[r] = mnew;
      float p0 = exp2f(a0[r] - mnew);
      float p1 = exp2f(a1[r] - mnew);
      pb0[r] = f2b(p0); pb1[r] = f2b(p1);
      psum[r] = b2f(pb0[r]) + b2f(pb1[r]);  // sum the ROUNDED p: l matches PV exactly
    }
#pragma unroll
    for (int off = 1; off < 16; off <<= 1)
#pragma unroll
      for (int r = 0; r < 4; ++r) psum[r] += __shfl_xor(psum[r], off);
#pragma unroll
    for (int r = 0; r < 4; ++r) {
      l_r[r] = l_r[r] * alpha[r] + psum[r];
      Psw[(quad * 4 + r) * PSS + lrow] = pb0[r];
      Psw[(quad * 4 + r) * PSS + 16 + lrow] = pb1[r];
#pragma unroll
      for (int nt = 0; nt < 4; ++nt) o[nt][r] *= alpha[r];
    }

    // P: C-layout -> A-layout via per-wave LDS round-trip (no cross-wave barrier)
    short8 pf = *(const short8*)(Psw + lrow * PSS + quad * 8);
#pragma unroll
    for (int nt = 0; nt < 4; ++nt) {
      short8 vf = *(const short8*)(Vt + (nt * 16 + lrow) * VTS + quad * 8);
      o[nt] = __builtin_amdgcn_mfma_f32_16x16x32_bf16(pf, vf, o[nt], 0, 0, 0);
    }
  }

  // epilogue: normalize, write fp32 out[b][n*16+s][h*64+dh]
#pragma unroll
  for (int r = 0; r < 4; ++r) {
    int n = qt * QT + wave * 16 + quad * 4 + r;
    float inv = 1.0f / l_r[r];
    float* op = out + (seqbase + (size_t)n * BSn) * Dsz + h * DHn;
#pragma unroll
    for (int nt = 0; nt < 4; ++nt) op[nt * 16 + lrow] = o[nt][r] * inv;
  }
}

// ---------------- launch ----------------
extern "C" void kernel_launch(void* const* d_in, const int* in_sizes, int n_in,
                              void* d_out, int out_size, void* d_ws, size_t ws_size,
                              hipStream_t stream) {
  const float* x  = (const float*)d_in[0];
  const float* Wq = (const float*)d_in[1];
  const float* bq = (const float*)d_in[2];
  const float* Wk = (const float*)d_in[3];
  const float* bk = (const float*)d_in[4];
  const float* Wv = (const float*)d_in[5];
  const float* bv = (const float*)d_in[6];
  float* out = (float*)d_out;

  // workspace layout (bytes): qkv bf16 100.66MB | x bf16 33.55MB | Wc bf16 1.57MB
  uint16_t* qkv = (uint16_t*)d_ws;
  uint16_t* xb  = qkv + (size_t)MROWS * NQKV;
  uint16_t* wc  = xb + (size_t)MROWS * Dsz;

  hipLaunchKernelGGL(cvt_x_kernel, dim3(MROWS * Dsz / 1024), dim3(256), 0, stream, x, xb);
  hipLaunchKernelGGL(cvt_w_kernel, dim3(NQKV * Dsz / 1024), dim3(256), 0, stream,
                     Wq, Wk, Wv, wc);
  hipLaunchKernelGGL(gemm_qkv, dim3(MROWS / BM, NQKV / BN), dim3(256), 0, stream,
                     xb, wc, bq, bk, bv, qkv);
  hipLaunchKernelGGL(attn_kernel, dim3(Bsz * BSn * Hn * (NBn / QT)), dim3(256), 0, stream,
                     qkv, out);
}

// Round 2
// 303.372 us; speedup vs baseline: 1.4020x; 1.4020x over previous
//
#include <hip/hip_runtime.h>
#include <hip/hip_bf16.h>
#include <cstdint>
#include <cstddef>

// Problem constants
#define Bsz 4
#define Tsz 8192
#define Dsz 512
#define Hn 8
#define BSn 16
#define NBn 512     // T/BS blocks (attention sequence length)
#define DHn 64      // head dim
#define NQKV 1536   // 3*D
#define MROWS 32768 // B*T

// softmax scale folded with log2(e), applied to Q at gemm epilogue
#define SCL 0.06375870136f
// fixed softmax max (exp2 domain); scores sigma~0.5, max~3.2 -> constant offset
// cancels exactly in p/sum(p), no overflow possible
#define ATT_M 8.0f

typedef __attribute__((ext_vector_type(8))) short short8;
typedef __attribute__((ext_vector_type(4))) float float4f;

__device__ __forceinline__ uint16_t f2b(float f) {
  union { float f; uint32_t u; } v; v.f = f;
  uint32_t u = v.u;
  return (uint16_t)((u + 0x7fffu + ((u >> 16) & 1u)) >> 16);  // RNE
}

// pack two f32 -> (bf16(b)<<16)|bf16(a), round-half-up (bias ~2^-17, negligible)
__device__ __forceinline__ uint32_t pk2(float a, float b) {
  union { float f; uint32_t u; } x, y; x.f = a; y.f = b;
  return __builtin_amdgcn_perm(y.u + 0x8000u, x.u + 0x8000u, 0x07060302u);
}

// async 16B global -> LDS (wave-uniform LDS base + lane*16)
__device__ __forceinline__ void gl_lds16(const void* g, void* l) {
  __builtin_amdgcn_global_load_lds(
      (const __attribute__((address_space(1))) unsigned int*)g,
      (__attribute__((address_space(3))) unsigned int*)l, 16, 0, 0);
}

// ---------------- convert kernels ----------------
__global__ void cvt_x_kernel(const float* __restrict__ x, uint16_t* __restrict__ xb) {
  int i = (blockIdx.x * 256 + threadIdx.x) * 4;
  float4 v = *(const float4*)(x + i);
  union { uint16_t u16[4]; uint64_t u64; } o;
  o.u16[0] = f2b(v.x); o.u16[1] = f2b(v.y); o.u16[2] = f2b(v.z); o.u16[3] = f2b(v.w);
  *(uint64_t*)(xb + i) = o.u64;
}

__global__ void cvt_w_kernel(const float* __restrict__ Wq, const float* __restrict__ Wk,
                             const float* __restrict__ Wv, uint16_t* __restrict__ wc) {
  int i = (blockIdx.x * 256 + threadIdx.x) * 4;  // i < 1536*512
  int row = i >> 9;
  int col = i & 511;
  const float* src = (row < 512) ? Wq : ((row < 1024) ? Wk : Wv);
  float4 v = *(const float4*)(src + (size_t)(row & 511) * 512 + col);
  union { uint16_t u16[4]; uint64_t u64; } o;
  o.u16[0] = f2b(v.x); o.u16[1] = f2b(v.y); o.u16[2] = f2b(v.z); o.u16[3] = f2b(v.w);
  *(uint64_t*)(wc + i) = o.u64;
}

// ---------------- QKV projection GEMM ----------------
// Y[M=32768, N=1536] = Xb[M,512] * Wc[N,512]^T + bias.
// Epilogue scatters: Q -> Qp[(b,s,h)][nb][dh] (scaled by SCL), K -> Kp same
// layout, V -> Vtmp[token][512] (transposed later by vtrans).
#define BM 128
#define BN 128
#define BK 32

__global__ __launch_bounds__(256) void gemm_qkv(
    const uint16_t* __restrict__ Xb, const uint16_t* __restrict__ Wc,
    const float* __restrict__ bq, const float* __restrict__ bkp,
    const float* __restrict__ bv, uint16_t* __restrict__ Qp,
    uint16_t* __restrict__ Kp, uint16_t* __restrict__ Vtmp) {
  __shared__ uint16_t As[BM * BK];
  __shared__ uint16_t Bs[BN * BK];
  const int tid = threadIdx.x;
  const int wave = tid >> 6, lane = tid & 63;
  const int lrow = lane & 15, quad = lane >> 4;
  const int n0 = blockIdx.x * BN;   // N-tile fastest: A reused by 12 consecutive blocks
  const int m0 = blockIdx.y * BM;
  const int wm = (wave >> 1) * 64, wn = (wave & 1) * 64;

  float4f acc[4][4] = {};

  for (int k0 = 0; k0 < Dsz; k0 += BK) {
    __syncthreads();
#pragma unroll
    for (int p = 0; p < 2; ++p) {
      int cbase = p * 256 + wave * 64;   // wave-uniform chunk base
      int c = cbase + lane;
      int row = c >> 2, kc = (c & 3) * 8;
      gl_lds16(Xb + (size_t)(m0 + row) * Dsz + k0 + kc, As + cbase * 8);
      gl_lds16(Wc + (size_t)(n0 + row) * Dsz + k0 + kc, Bs + cbase * 8);
    }
    __syncthreads();

    short8 af[4], bf[4];
#pragma unroll
    for (int i = 0; i < 4; ++i) {
      af[i] = *(const short8*)(As + (wm + i * 16 + lrow) * BK + quad * 8);
      bf[i] = *(const short8*)(Bs + (wn + i * 16 + lrow) * BK + quad * 8);
    }
#pragma unroll
    for (int i = 0; i < 4; ++i)
#pragma unroll
      for (int j = 0; j < 4; ++j)
        acc[i][j] = __builtin_amdgcn_mfma_f32_16x16x32_bf16(af[i], bf[j], acc[i][j], 0, 0, 0);
  }

  // epilogue
  const int region = n0 >> 9;  // 0=Q, 1=K, 2=V (128 | 512 so no tile crosses)
  const float* bias = (region == 0) ? bq : ((region == 1) ? bkp : bv);
  const float mult = (region == 0) ? SCL : 1.0f;
  const int bb = m0 >> 13;                              // batch (tile never crosses)
  const int nbbase = ((m0 & 8191) >> 4) + (wm >> 4);    // s = quad*4+r, nb = nbbase+i

  if (region < 2) {
    uint16_t* dst = (region == 0) ? Qp : Kp;
#pragma unroll
    for (int j = 0; j < 4; ++j) {
      int nl = (n0 + wn + j * 16 + lrow) & 511;
      int hh = nl >> 6, dh = nl & 63;
      float bval = bias[nl];
      // addr = ((b*16+s)*8+h)*32768 + nb*64 + dh
      size_t base = (size_t)bb * 4194304 + (size_t)hh * 32768 +
                    (size_t)nbbase * 64 + dh + (size_t)(quad * 4) * 262144;
#pragma unroll
      for (int i = 0; i < 4; ++i)
#pragma unroll
        for (int r = 0; r < 4; ++r)
          dst[base + (size_t)r * 262144 + (size_t)i * 64] =
              f2b((acc[i][j][r] + bval) * mult);
    }
  } else {
#pragma unroll
    for (int j = 0; j < 4; ++j) {
      int nl = (n0 + wn + j * 16 + lrow) & 511;
      float bval = bias[nl];
#pragma unroll
      for (int i = 0; i < 4; ++i) {
        int tok = m0 + wm + i * 16 + quad * 4;
#pragma unroll
        for (int r = 0; r < 4; ++r)
          Vtmp[(size_t)(tok + r) * 512 + nl] = f2b(acc[i][j][r] + bval);
      }
    }
  }
}

// ---------------- V transpose: Vtmp[32768][512] -> Vt[(b,s,h)][dh=64][nb=512] ----------------
__global__ __launch_bounds__(256) void vtrans(const uint16_t* __restrict__ Vtmp,
                                              uint16_t* __restrict__ Vt) {
  __shared__ uint16_t tile[64 * 64];  // [nb_local][dh], 16B chunks XOR-swizzled by row
  int bx = blockIdx.x;
  const int nt = bx & 7; bx >>= 3;
  const int h = bx & 7; bx >>= 3;
  const int s = bx & 15;
  const int b = bx >> 4;
  const int tid = threadIdx.x;

  {  // read 64 tokens x 64 dh; thread: row i, two 16B chunks
    int i = tid >> 2;
    int token = b * Tsz + (nt * 64 + i) * BSn + s;
    const uint16_t* src = Vtmp + (size_t)token * 512 + h * 64;
#pragma unroll
    for (int hh = 0; hh < 2; ++hh) {
      int ch = (tid & 3) * 2 + hh;
      short8 v = *(const short8*)(src + ch * 8);
      int pc = ch ^ (i & 7);
      *(short8*)(tile + i * 64 + pc * 8) = v;
    }
  }
  __syncthreads();
  {  // write: wave-major dh for conflict-free column gather
    int dh = tid & 63, seg = tid >> 6;
    short8 v1, v2;
#pragma unroll
    for (int k = 0; k < 8; ++k) {
      int nb_l = seg * 16 + k;
      v1[k] = (short)tile[nb_l * 64 + (((dh >> 3) ^ (nb_l & 7)) * 8) + (dh & 7)];
    }
#pragma unroll
    for (int k = 0; k < 8; ++k) {
      int nb_l = seg * 16 + 8 + k;
      v2[k] = (short)tile[nb_l * 64 + (((dh >> 3) ^ (nb_l & 7)) * 8) + (dh & 7)];
    }
    size_t obase = ((((size_t)b * 16 + s) * 8 + h) * 64 + dh) * 512 + nt * 64 + seg * 16;
    *(short8*)(Vt + obase) = v1;
    *(short8*)(Vt + obase + 8) = v2;
  }
}

// ---------------- fused block attention, S^T orientation, fixed-max softmax ----------------
// Block: one (b,s,h) x 256 q-rows. Wave: 64 q (4 subtiles of 16). KT=32 kv/iter.
__global__ __launch_bounds__(256, 2) void attn_kernel(
    const uint16_t* __restrict__ Qp, const uint16_t* __restrict__ Kp,
    const uint16_t* __restrict__ Vt, float* __restrict__ out) {
  __shared__ uint16_t Ks[32 * 64];     // K tile, rows 128B, chunk pos p = c ^ (r&7)
  __shared__ uint16_t Vs[64 * 32];     // V^T tile, rows 64B, p = c ^ ((r>>1)&3)
  __shared__ uint16_t Ps[4][16 * 32];  // per-wave P [q][kv], p = c ^ ((q>>1)&3)

  int bx = blockIdx.x;
  const int qh = bx & 1; bx >>= 1;
  const int h = bx & 7; bx >>= 3;
  const int s = bx & 15;
  const int b = bx >> 4;

  const int tid = threadIdx.x;
  const int w = tid >> 6, lane = tid & 63;
  const int lrow = lane & 15, quad = lane >> 4;

  const size_t sh = (((size_t)b * 16 + s) * 8 + h);
  const uint16_t* Qb = Qp + (sh << 15);   // [512 nb][64 dh]
  const uint16_t* Kb = Kp + (sh << 15);   // [512 nb][64 dh]
  const uint16_t* Vb = Vt + (sh << 15);   // [64 dh][512 nb]

  // Q B-fragments (persistent): 4 q-subtiles x 2 dh-chunks
  short8 qB[4][2];
  const int q0 = qh * 256 + w * 64;
#pragma unroll
  for (int qs = 0; qs < 4; ++qs) {
    const uint16_t* qp = Qb + (size_t)(q0 + qs * 16 + lrow) * 64;
    qB[qs][0] = *(const short8*)(qp + quad * 8);
    qB[qs][1] = *(const short8*)(qp + 32 + quad * 8);
  }

  float4f O[4][4] = {};                 // [dh tile][q subtile], C-layout (col=q)
  float l_acc[4] = {0.f, 0.f, 0.f, 0.f};

  // staging index precompute (XOR chunk-position swizzles; global side is free)
  const int kr = w * 8 + (lane >> 3);
  const int kcs = (lane & 7) ^ (kr & 7);
  const int vr = w * 16 + (lane >> 2);
  const int vcs = (lane & 3) ^ ((vr >> 1) & 3);

  uint16_t* Psw = Ps[w];
  const int sw = (lrow >> 1) & 3;

  for (int kv0 = 0; kv0 < NBn; kv0 += 32) {
    __syncthreads();
    gl_lds16(Kb + (size_t)(kv0 + kr) * 64 + kcs * 8, Ks + w * 512);
    gl_lds16(Vb + (size_t)vr * 512 + kv0 + vcs * 8, Vs + w * 512);
    __syncthreads();

    // K A-fragments: 2 kv-tiles x 2 dh-chunks
    short8 kA[2][2];
#pragma unroll
    for (int kt = 0; kt < 2; ++kt) {
      int row = kt * 16 + lrow;
#pragma unroll
      for (int kc = 0; kc < 2; ++kc) {
        int cc = (kc * 4 + quad) ^ (row & 7);
        kA[kt][kc] = *(const short8*)(Ks + row * 64 + cc * 8);
      }
    }
    // V^T A-fragments: 4 dh-tiles (k = 32 kv)
    short8 vA[4];
#pragma unroll
    for (int dt = 0; dt < 4; ++dt) {
      int row = dt * 16 + lrow;
      vA[dt] = *(const short8*)(Vs + row * 32 + (quad ^ ((row >> 1) & 3)) * 8);
    }

#pragma unroll
    for (int qs = 0; qs < 4; ++qs) {
      // S^T tiles [kv 16][q 16], two kv-tiles
      float4f c0 = {}, c1 = {};
      c0 = __builtin_amdgcn_mfma_f32_16x16x32_bf16(kA[0][0], qB[qs][0], c0, 0, 0, 0);
      c0 = __builtin_amdgcn_mfma_f32_16x16x32_bf16(kA[0][1], qB[qs][1], c0, 0, 0, 0);
      c1 = __builtin_amdgcn_mfma_f32_16x16x32_bf16(kA[1][0], qB[qs][0], c1, 0, 0, 0);
      c1 = __builtin_amdgcn_mfma_f32_16x16x32_bf16(kA[1][1], qB[qs][1], c1, 0, 0, 0);

      // fixed-max softmax: p = exp2(s - M); l sums raw p (rounding ~cancels)
      float p00 = exp2f(c0[0] - ATT_M), p01 = exp2f(c0[1] - ATT_M);
      float p02 = exp2f(c0[2] - ATT_M), p03 = exp2f(c0[3] - ATT_M);
      float p10 = exp2f(c1[0] - ATT_M), p11 = exp2f(c1[1] - ATT_M);
      float p12 = exp2f(c1[2] - ATT_M), p13 = exp2f(c1[3] - ATT_M);
      l_acc[qs] += (p00 + p01 + p02 + p03) + (p10 + p11 + p12 + p13);

      // packed b64 writes: P[q=lrow][kv = kt*16 + quad*4 + r]
      uint32_t d0 = pk2(p00, p01), d1 = pk2(p02, p03);
      uint32_t d2 = pk2(p10, p11), d3 = pk2(p12, p13);
      int half = (quad & 1) * 4;
      *(uint2*)(Psw + lrow * 32 + (((quad >> 1)) ^ sw) * 8 + half) = make_uint2(d0, d1);
      *(uint2*)(Psw + lrow * 32 + ((2 + (quad >> 1)) ^ sw) * 8 + half) = make_uint2(d2, d3);

      // read back as B-fragment: B[k=kv=quad*8+j][n=q=lrow]
      short8 pB = *(const short8*)(Psw + lrow * 32 + (quad ^ sw) * 8);
#pragma unroll
      for (int dt = 0; dt < 4; ++dt)
        O[dt][qs] = __builtin_amdgcn_mfma_f32_16x16x32_bf16(vA[dt], pB, O[dt][qs], 0, 0, 0);
    }
  }

  // epilogue: reduce l across quads (kv partials), normalize, write fp32
#pragma unroll
  for (int qs = 0; qs < 4; ++qs) {
    float l = l_acc[qs];
    l += __shfl_xor(l, 16);
    l += __shfl_xor(l, 32);
    float inv = 1.0f / l;
    int qg = q0 + qs * 16 + lrow;   // nb index of this lane's q column
    float* op = out + ((size_t)b * Tsz + (size_t)qg * 16 + s) * Dsz + h * 64;
#pragma unroll
    for (int dt = 0; dt < 4; ++dt) {
      float4 vv;
      vv.x = O[dt][qs][0] * inv; vv.y = O[dt][qs][1] * inv;
      vv.z = O[dt][qs][2] * inv; vv.w = O[dt][qs][3] * inv;
      *(float4*)(op + dt * 16 + quad * 4) = vv;
    }
  }
}

// ---------------- launch ----------------
extern "C" void kernel_launch(void* const* d_in, const int* in_sizes, int n_in,
                              void* d_out, int out_size, void* d_ws, size_t ws_size,
                              hipStream_t stream) {
  const float* x  = (const float*)d_in[0];
  const float* Wq = (const float*)d_in[1];
  const float* bq = (const float*)d_in[2];
  const float* Wk = (const float*)d_in[3];
  const float* bk = (const float*)d_in[4];
  const float* Wv = (const float*)d_in[5];
  const float* bv = (const float*)d_in[6];
  float* out = (float*)d_out;

  // workspace: Qp | Kp | Vtmp | xb | wc ; Vt aliases xb (gemm done with xb first)
  uint16_t* Qp   = (uint16_t*)d_ws;
  uint16_t* Kp   = Qp + (size_t)16777216;
  uint16_t* Vtmp = Kp + (size_t)16777216;
  uint16_t* xb   = Vtmp + (size_t)16777216;
  uint16_t* wc   = xb + (size_t)16777216;
  uint16_t* Vt   = xb;  // alias

  hipLaunchKernelGGL(cvt_x_kernel, dim3(MROWS * Dsz / 1024), dim3(256), 0, stream, x, xb);
  hipLaunchKernelGGL(cvt_w_kernel, dim3(NQKV * Dsz / 1024), dim3(256), 0, stream,
                     Wq, Wk, Wv, wc);
  hipLaunchKernelGGL(gemm_qkv, dim3(NQKV / BN, MROWS / BM), dim3(256), 0, stream,
                     xb, wc, bq, bk, bv, Qp, Kp, Vtmp);
  hipLaunchKernelGGL(vtrans, dim3(Bsz * BSn * Hn * 8), dim3(256), 0, stream, Vtmp, Vt);
  hipLaunchKernelGGL(attn_kernel, dim3(Bsz * BSn * Hn * 2), dim3(256), 0, stream,
                     Qp, Kp, Vt, out);
}

// Round 3
// 270.876 us; speedup vs baseline: 1.5701x; 1.1200x over previous
//
#include <hip/hip_runtime.h>
#include <hip/hip_bf16.h>
#include <cstdint>
#include <cstddef>

// Problem constants
#define Bsz 4
#define Tsz 8192
#define Dsz 512
#define Hn 8
#define BSn 16
#define NBn 512     // T/BS blocks (attention sequence length)
#define DHn 64      // head dim
#define NQKV 1536   // 3*D
#define MROWS 32768 // B*T

// softmax scale folded with log2(e), applied to Q at gemm epilogue
#define SCL 0.06375870136f
// fixed softmax max (exp2 domain); constant offset cancels in p/sum(p)
#define ATT_M 8.0f

typedef __attribute__((ext_vector_type(8))) short short8;
typedef __attribute__((ext_vector_type(4))) float float4f;

__device__ __forceinline__ uint16_t f2b(float f) {
  union { float f; uint32_t u; } v; v.f = f;
  uint32_t u = v.u;
  return (uint16_t)((u + 0x7fffu + ((u >> 16) & 1u)) >> 16);  // RNE
}

// pack two f32 -> (bf16(b)<<16)|bf16(a), TRUNCATING (1 instr); l sums the
// same raw p so softmax normalization stays self-consistent
__device__ __forceinline__ uint32_t pk2t(float a, float b) {
  union { float f; uint32_t u; } x, y; x.f = a; y.f = b;
  return __builtin_amdgcn_perm(y.u, x.u, 0x07060302u);
}

// async 16B global -> LDS (wave-uniform LDS base + lane*16)
__device__ __forceinline__ void gl_lds16(const void* g, void* l) {
  __builtin_amdgcn_global_load_lds(
      (const __attribute__((address_space(1))) unsigned int*)g,
      (__attribute__((address_space(3))) unsigned int*)l, 16, 0, 0);
}

// ---------------- fused convert kernel (x and Wq/Wk/Wv -> bf16) ----------------
#define XBLK (MROWS * Dsz / 1024)   // 16384 blocks for x
__global__ void cvt_kernel(const float* __restrict__ x, const float* __restrict__ Wq,
                           const float* __restrict__ Wk, const float* __restrict__ Wv,
                           uint16_t* __restrict__ xb, uint16_t* __restrict__ wc) {
  int bid = blockIdx.x;
  if (bid < XBLK) {
    int i = (bid * 256 + threadIdx.x) * 4;
    float4 v = *(const float4*)(x + i);
    union { uint16_t u16[4]; uint64_t u64; } o;
    o.u16[0] = f2b(v.x); o.u16[1] = f2b(v.y); o.u16[2] = f2b(v.z); o.u16[3] = f2b(v.w);
    *(uint64_t*)(xb + i) = o.u64;
  } else {
    int i = ((bid - XBLK) * 256 + threadIdx.x) * 4;  // i < 1536*512
    int row = i >> 9;
    int col = i & 511;
    const float* src = (row < 512) ? Wq : ((row < 1024) ? Wk : Wv);
    float4 v = *(const float4*)(src + (size_t)(row & 511) * 512 + col);
    union { uint16_t u16[4]; uint64_t u64; } o;
    o.u16[0] = f2b(v.x); o.u16[1] = f2b(v.y); o.u16[2] = f2b(v.z); o.u16[3] = f2b(v.w);
    *(uint64_t*)(wc + i) = o.u64;
  }
}

// ---------------- QKV projection GEMM ----------------
// Y[M=32768, N=1536] = Xb[M,512] * Wc[N,512]^T + bias.  BK=64, XOR-swizzled LDS,
// XCD-aware block swizzle (12 N-tiles of one m-tile stay on one XCD).
#define BM 128
#define BN 128
#define BK 64

__global__ __launch_bounds__(256) void gemm_qkv(
    const uint16_t* __restrict__ Xb, const uint16_t* __restrict__ Wc,
    const float* __restrict__ bq, const float* __restrict__ bkp,
    const float* __restrict__ bv, uint16_t* __restrict__ Qp,
    uint16_t* __restrict__ Kp, uint16_t* __restrict__ Vtmp) {
  __shared__ uint16_t As[BM * BK];  // 16KB, row=64 elems=8 chunks, pos = c ^ (row&7)
  __shared__ uint16_t Bs[BN * BK];
  const int tid = threadIdx.x;
  const int wave = tid >> 6, lane = tid & 63;
  const int lrow = lane & 15, quad = lane >> 4;

  // XCD swizzle: consecutive blockIdx round-robin over 8 XCDs; keep one m-tile's
  // 12 n-blocks on one XCD, m-tiles partitioned 32-per-XCD.
  int g = blockIdx.x;
  int xcd = g & 7, ii = g >> 3;        // ii in [0,384)
  int mt = xcd * 32 + ii / 12;
  int nt = ii - (ii / 12) * 12;
  const int m0 = mt * BM;
  const int n0 = nt * BN;
  const int wm = (wave >> 1) * 64, wn = (wave & 1) * 64;

  float4f acc[4][4] = {};

  for (int k0 = 0; k0 < Dsz; k0 += BK) {
    __syncthreads();
#pragma unroll
    for (int p = 0; p < 4; ++p) {
      int cbase = p * 256 + wave * 64;   // wave-uniform chunk base
      int c = cbase + lane;
      int row = c >> 3, pos = c & 7;
      int kc = (pos ^ (row & 7)) * 8;    // swizzle on the GLOBAL side (free)
      gl_lds16(Xb + (size_t)(m0 + row) * Dsz + k0 + kc, As + cbase * 8);
      gl_lds16(Wc + (size_t)(n0 + row) * Dsz + k0 + kc, Bs + cbase * 8);
    }
    __syncthreads();

#pragma unroll
    for (int h = 0; h < 2; ++h) {
      short8 af[4], bf[4];
#pragma unroll
      for (int i = 0; i < 4; ++i) {
        int rowA = wm + i * 16 + lrow;
        af[i] = *(const short8*)(As + rowA * BK + (((h * 4 + quad) ^ (rowA & 7)) * 8));
        int rowB = wn + i * 16 + lrow;
        bf[i] = *(const short8*)(Bs + rowB * BK + (((h * 4 + quad) ^ (rowB & 7)) * 8));
      }
#pragma unroll
      for (int i = 0; i < 4; ++i)
#pragma unroll
        for (int j = 0; j < 4; ++j)
          acc[i][j] = __builtin_amdgcn_mfma_f32_16x16x32_bf16(af[i], bf[j], acc[i][j], 0, 0, 0);
    }
  }

  // epilogue
  const int region = n0 >> 9;  // 0=Q, 1=K, 2=V (128 | 512 so no tile crosses)
  const float* bias = (region == 0) ? bq : ((region == 1) ? bkp : bv);
  const float mult = (region == 0) ? SCL : 1.0f;
  const int bb = m0 >> 13;                              // batch (tile never crosses)
  const int nbbase = ((m0 & 8191) >> 4) + (wm >> 4);    // s = quad*4+r, nb = nbbase+i

  if (region < 2) {
    uint16_t* dst = (region == 0) ? Qp : Kp;
#pragma unroll
    for (int j = 0; j < 4; ++j) {
      int nl = (n0 + wn + j * 16 + lrow) & 511;
      int hh = nl >> 6, dh = nl & 63;
      float bval = bias[nl];
      // addr = ((b*16+s)*8+h)*32768 + nb*64 + dh
      size_t base = (size_t)bb * 4194304 + (size_t)hh * 32768 +
                    (size_t)nbbase * 64 + dh + (size_t)(quad * 4) * 262144;
#pragma unroll
      for (int i = 0; i < 4; ++i)
#pragma unroll
        for (int r = 0; r < 4; ++r)
          dst[base + (size_t)r * 262144 + (size_t)i * 64] =
              f2b((acc[i][j][r] + bval) * mult);
    }
  } else {
#pragma unroll
    for (int j = 0; j < 4; ++j) {
      int nl = (n0 + wn + j * 16 + lrow) & 511;
      float bval = bias[nl];
#pragma unroll
      for (int i = 0; i < 4; ++i) {
        int tok = m0 + wm + i * 16 + quad * 4;
#pragma unroll
        for (int r = 0; r < 4; ++r)
          Vtmp[(size_t)(tok + r) * 512 + nl] = f2b(acc[i][j][r] + bval);
      }
    }
  }
}

// ---------------- V transpose: Vtmp[32768][512] -> Vt[(b,s,h)][dh=64][nb=512] ----------------
__global__ __launch_bounds__(256) void vtrans(const uint16_t* __restrict__ Vtmp,
                                              uint16_t* __restrict__ Vt) {
  __shared__ uint16_t tile[64 * 64];  // [nb_local][dh], 16B chunks XOR-swizzled by row
  int bx = blockIdx.x;
  const int nt = bx & 7; bx >>= 3;
  const int h = bx & 7; bx >>= 3;
  const int s = bx & 15;
  const int b = bx >> 4;
  const int tid = threadIdx.x;

  {  // read 64 tokens x 64 dh; thread: row i, two 16B chunks
    int i = tid >> 2;
    int token = b * Tsz + (nt * 64 + i) * BSn + s;
    const uint16_t* src = Vtmp + (size_t)token * 512 + h * 64;
#pragma unroll
    for (int hh = 0; hh < 2; ++hh) {
      int ch = (tid & 3) * 2 + hh;
      short8 v = *(const short8*)(src + ch * 8);
      int pc = ch ^ (i & 7);
      *(short8*)(tile + i * 64 + pc * 8) = v;
    }
  }
  __syncthreads();
  {  // write: wave-major dh for conflict-free column gather
    int dh = tid & 63, seg = tid >> 6;
    short8 v1, v2;
#pragma unroll
    for (int k = 0; k < 8; ++k) {
      int nb_l = seg * 16 + k;
      v1[k] = (short)tile[nb_l * 64 + (((dh >> 3) ^ (nb_l & 7)) * 8) + (dh & 7)];
    }
#pragma unroll
    for (int k = 0; k < 8; ++k) {
      int nb_l = seg * 16 + 8 + k;
      v2[k] = (short)tile[nb_l * 64 + (((dh >> 3) ^ (nb_l & 7)) * 8) + (dh & 7)];
    }
    size_t obase = ((((size_t)b * 16 + s) * 8 + h) * 64 + dh) * 512 + nt * 64 + seg * 16;
    *(short8*)(Vt + obase) = v1;
    *(short8*)(Vt + obase + 8) = v2;
  }
}

// ---------------- fused block attention, S^T orientation, fixed-max softmax ----------------
// Block: one (b,s,h) x 256 q-rows. Wave: 64 q (4 subtiles of 16). KT=32 kv/iter.
// Phase-split per iter: S-phase (all qs -> P in per-wave LDS), then PV-phase.
__global__ __launch_bounds__(256, 3) void attn_kernel(
    const uint16_t* __restrict__ Qp, const uint16_t* __restrict__ Kp,
    const uint16_t* __restrict__ Vt, float* __restrict__ out) {
  __shared__ uint16_t Ks[32 * 64];        // K tile, rows 128B, chunk pos = c ^ (r&7)
  __shared__ uint16_t Vs[64 * 32];        // V^T tile, rows 64B, pos = c ^ ((r>>1)&3)
  __shared__ uint16_t Ps[4][4][16 * 32];  // [wave][qs] P [q][kv], pos = c ^ ((q>>1)&3)

  int bx = blockIdx.x;
  const int qh = bx & 1; bx >>= 1;
  const int h = bx & 7; bx >>= 3;
  const int s = bx & 15;
  const int b = bx >> 4;

  const int tid = threadIdx.x;
  const int w = tid >> 6, lane = tid & 63;
  const int lrow = lane & 15, quad = lane >> 4;

  const size_t sh = (((size_t)b * 16 + s) * 8 + h);
  const uint16_t* Qb = Qp + (sh << 15);   // [512 nb][64 dh]
  const uint16_t* Kb = Kp + (sh << 15);   // [512 nb][64 dh]
  const uint16_t* Vb = Vt + (sh << 15);   // [64 dh][512 nb]

  // Q B-fragments (persistent): 4 q-subtiles x 2 dh-chunks
  short8 qB[4][2];
  const int q0 = qh * 256 + w * 64;
#pragma unroll
  for (int qs = 0; qs < 4; ++qs) {
    const uint16_t* qp = Qb + (size_t)(q0 + qs * 16 + lrow) * 64;
    qB[qs][0] = *(const short8*)(qp + quad * 8);
    qB[qs][1] = *(const short8*)(qp + 32 + quad * 8);
  }

  float4f O[4][4] = {};                 // [dh tile][q subtile], C-layout (col=q)
  float l_acc[4] = {0.f, 0.f, 0.f, 0.f};

  // staging index precompute (XOR chunk-position swizzles; global side is free)
  const int kr = w * 8 + (lane >> 3);
  const int kcs = (lane & 7) ^ (kr & 7);
  const int vr = w * 16 + (lane >> 2);
  const int vcs = (lane & 3) ^ ((vr >> 1) & 3);

  const int sw = (lrow >> 1) & 3;

  for (int kv0 = 0; kv0 < NBn; kv0 += 32) {
    __syncthreads();
    gl_lds16(Kb + (size_t)(kv0 + kr) * 64 + kcs * 8, Ks + w * 512);
    gl_lds16(Vb + (size_t)vr * 512 + kv0 + vcs * 8, Vs + w * 512);
    __syncthreads();

    // ---- S-phase: K A-fragments, scores, exp2, pack into Ps ----
    {
      short8 kA[2][2];
#pragma unroll
      for (int kt = 0; kt < 2; ++kt) {
        int row = kt * 16 + lrow;
#pragma unroll
        for (int kc = 0; kc < 2; ++kc) {
          int cc = (kc * 4 + quad) ^ (row & 7);
          kA[kt][kc] = *(const short8*)(Ks + row * 64 + cc * 8);
        }
      }
#pragma unroll
      for (int qs = 0; qs < 4; ++qs) {
        float4f c0 = {}, c1 = {};
        c0 = __builtin_amdgcn_mfma_f32_16x16x32_bf16(kA[0][0], qB[qs][0], c0, 0, 0, 0);
        c0 = __builtin_amdgcn_mfma_f32_16x16x32_bf16(kA[0][1], qB[qs][1], c0, 0, 0, 0);
        c1 = __builtin_amdgcn_mfma_f32_16x16x32_bf16(kA[1][0], qB[qs][0], c1, 0, 0, 0);
        c1 = __builtin_amdgcn_mfma_f32_16x16x32_bf16(kA[1][1], qB[qs][1], c1, 0, 0, 0);

        float p00 = __builtin_amdgcn_exp2f(c0[0] - ATT_M);
        float p01 = __builtin_amdgcn_exp2f(c0[1] - ATT_M);
        float p02 = __builtin_amdgcn_exp2f(c0[2] - ATT_M);
        float p03 = __builtin_amdgcn_exp2f(c0[3] - ATT_M);
        float p10 = __builtin_amdgcn_exp2f(c1[0] - ATT_M);
        float p11 = __builtin_amdgcn_exp2f(c1[1] - ATT_M);
        float p12 = __builtin_amdgcn_exp2f(c1[2] - ATT_M);
        float p13 = __builtin_amdgcn_exp2f(c1[3] - ATT_M);
        l_acc[qs] += ((p00 + p01) + (p02 + p03)) + ((p10 + p11) + (p12 + p13));

        uint32_t d0 = pk2t(p00, p01), d1 = pk2t(p02, p03);
        uint32_t d2 = pk2t(p10, p11), d3 = pk2t(p12, p13);
        uint16_t* Psq = Ps[w][qs];
        int half = (quad & 1) * 4;
        *(uint2*)(Psq + lrow * 32 + (((quad >> 1)) ^ sw) * 8 + half) = make_uint2(d0, d1);
        *(uint2*)(Psq + lrow * 32 + ((2 + (quad >> 1)) ^ sw) * 8 + half) = make_uint2(d2, d3);
      }
    }

    // ---- PV-phase: V^T A-fragments, P B-fragments, accumulate O ----
    {
      short8 vA[4];
#pragma unroll
      for (int dt = 0; dt < 4; ++dt) {
        int row = dt * 16 + lrow;
        vA[dt] = *(const short8*)(Vs + row * 32 + (quad ^ ((row >> 1) & 3)) * 8);
      }
#pragma unroll
      for (int qs = 0; qs < 4; ++qs) {
        short8 pB = *(const short8*)(Ps[w][qs] + lrow * 32 + (quad ^ sw) * 8);
#pragma unroll
        for (int dt = 0; dt < 4; ++dt)
          O[dt][qs] = __builtin_amdgcn_mfma_f32_16x16x32_bf16(vA[dt], pB, O[dt][qs], 0, 0, 0);
      }
    }
  }

  // epilogue: reduce l across quads (kv partials), normalize, write fp32
#pragma unroll
  for (int qs = 0; qs < 4; ++qs) {
    float l = l_acc[qs];
    l += __shfl_xor(l, 16);
    l += __shfl_xor(l, 32);
    float inv = 1.0f / l;
    int qg = q0 + qs * 16 + lrow;   // nb index of this lane's q column
    float* op = out + ((size_t)b * Tsz + (size_t)qg * 16 + s) * Dsz + h * 64;
#pragma unroll
    for (int dt = 0; dt < 4; ++dt) {
      float4 vv;
      vv.x = O[dt][qs][0] * inv; vv.y = O[dt][qs][1] * inv;
      vv.z = O[dt][qs][2] * inv; vv.w = O[dt][qs][3] * inv;
      *(float4*)(op + dt * 16 + quad * 4) = vv;
    }
  }
}

// ---------------- launch ----------------
extern "C" void kernel_launch(void* const* d_in, const int* in_sizes, int n_in,
                              void* d_out, int out_size, void* d_ws, size_t ws_size,
                              hipStream_t stream) {
  const float* x  = (const float*)d_in[0];
  const float* Wq = (const float*)d_in[1];
  const float* bq = (const float*)d_in[2];
  const float* Wk = (const float*)d_in[3];
  const float* bk = (const float*)d_in[4];
  const float* Wv = (const float*)d_in[5];
  const float* bv = (const float*)d_in[6];
  float* out = (float*)d_out;

  // workspace: Qp | Kp | Vtmp | xb | wc ; Vt aliases xb (gemm done with xb first)
  uint16_t* Qp   = (uint16_t*)d_ws;
  uint16_t* Kp   = Qp + (size_t)16777216;
  uint16_t* Vtmp = Kp + (size_t)16777216;
  uint16_t* xb   = Vtmp + (size_t)16777216;
  uint16_t* wc   = xb + (size_t)16777216;
  uint16_t* Vt   = xb;  // alias

  hipLaunchKernelGGL(cvt_kernel, dim3(XBLK + NQKV * Dsz / 1024), dim3(256), 0, stream,
                     x, Wq, Wk, Wv, xb, wc);
  hipLaunchKernelGGL(gemm_qkv, dim3((MROWS / BM) * (NQKV / BN)), dim3(256), 0, stream,
                     xb, wc, bq, bk, bv, Qp, Kp, Vtmp);
  hipLaunchKernelGGL(vtrans, dim3(Bsz * BSn * Hn * 8), dim3(256), 0, stream, Vtmp, Vt);
  hipLaunchKernelGGL(attn_kernel, dim3(Bsz * BSn * Hn * 2), dim3(256), 0, stream,
                     Qp, Kp, Vt, out);
}